// Round 9
// baseline (56.123 us; speedup 1.0000x reference)
//
#include <hip/hip_runtime.h>
#include <math.h>

#define GN 8192
#define BN 2
#define HN 256
#define WN 256
#define FRONT_K 8
#define EPS_T 1e-8f
#define ALPHA_T (1.0f / 255.0f)
#define TDIM 32                 // 32x32 tiles of 8x8 px per batch (r8 regression reverted)
#define NTILE (TDIM * TDIM)
#define CAP 256                 // per-tile list cap (mean ~54)

// ---------------------------------------------------------------------------
// Kernel 0: clear per-tile counters (BN*NTILE = 2048 u32).
// ---------------------------------------------------------------------------
__global__ __launch_bounds__(64) void pgr_clear(unsigned* __restrict__ cur)
{
    cur[blockIdx.x * 64 + threadIdx.x] = 0u;
}

// ---------------------------------------------------------------------------
// Kernel 1: prep + binning. One thread per (batch, gaussian):
//  - repack SoA records (original order)
//  - conservative bbox (alpha>=1/255 <=> sigma<=ln(255*op)) -> tile rect
//  - atomicAdd-append orig index to covered tiles' lists (append order is
//    irrelevant: raster rank-sorts each list by (depth,idx) deterministically)
// ---------------------------------------------------------------------------
__global__ __launch_bounds__(64) void pgr_prep(
    const float* __restrict__ means2d, const float* __restrict__ conics,
    const float* __restrict__ colors, const float* __restrict__ opac,
    float4* __restrict__ dat0, float4* __restrict__ dat1,
    float* __restrict__ dat2, unsigned* __restrict__ cur,
    unsigned* __restrict__ ent)
{
    int g = blockIdx.x * 64 + threadIdx.x;       // [0, BN*GN)
    int b = g >> 13, i = g & (GN - 1);
    float2 mxy = reinterpret_cast<const float2*>(means2d)[g];
    float mx = mxy.x, my = mxy.y;
    float ca = conics[3 * g], cb = conics[3 * g + 1], cc = conics[3 * g + 2];
    float r = colors[3 * g], g2 = colors[3 * g + 1], b3 = colors[3 * g + 2];
    float op = opac[g];

    dat0[g] = make_float4(mx, my, ca, cb);
    dat1[g] = make_float4(cc, op, r, g2);
    dat2[g] = b3;

    float s = (op > 0.f) ? (logf(255.0f * op) + 1e-4f) : -1.0f;
    if (s < 0.f) return;                          // alpha < 1/255 everywhere
    float det = fmaxf(ca * cc - cb * cb, 1e-12f);
    float dxm = sqrtf(2.f * s * cc / det) + 0.02f;
    float dym = sqrtf(2.f * s * ca / det) + 0.02f;
    // pixel centers x+0.5 inside [mx-dxm, mx+dxm]; +-1px conservative slack
    int x0 = (int)floorf(mx - dxm - 0.5f), x1 = (int)ceilf(mx + dxm - 0.5f);
    int y0 = (int)floorf(my - dym - 0.5f), y1 = (int)ceilf(my + dym - 0.5f);
    if (x1 < 0 || x0 > WN - 1 || y1 < 0 || y0 > HN - 1) return;
    x0 = max(x0, 0); x1 = min(x1, WN - 1);
    y0 = max(y0, 0); y1 = min(y1, HN - 1);
    int tx0 = x0 >> 3, tx1 = x1 >> 3, ty0 = y0 >> 3, ty1 = y1 >> 3;
    for (int ty = ty0; ty <= ty1; ++ty)
        for (int tx = tx0; tx <= tx1; ++tx) {
            int t = b * NTILE + ty * TDIM + tx;
            unsigned pos = atomicAdd(&cur[t], 1u);
            if (pos < CAP) ent[t * CAP + pos] = (unsigned)i;
        }
}

// rank of key k among s_key[0..L): broadcast LDS reads, no barriers, pipelined
__device__ __forceinline__ int rank_of(const unsigned long long* s_key,
                                       unsigned long long k, int L)
{
    int rank = 0, j = 0;
    for (; j + 4 <= L; j += 4) {
        unsigned long long k0 = s_key[j], k1 = s_key[j + 1];
        unsigned long long k2 = s_key[j + 2], k3 = s_key[j + 3];
        rank += (int)(k0 < k) + (int)(k1 < k) + (int)(k2 < k) + (int)(k3 < k);
    }
    for (; j < L; ++j) rank += (int)(s_key[j] < k);
    return rank;
}

// ---------------------------------------------------------------------------
// Kernel 2: raster. 64 threads = 1 wave = one 8x8 tile.
// r9 restructure (mask-then-blend): kept_i is compositing-state-independent
// and at most FRONT_K=8 candidates contribute per pixel. Phase A streams all
// candidates in sorted order (s_ord indirection; no record re-scatter) with
// ZERO loop-carried deps -> 16-wide ILP, building a 4xu64 kept bitmask.
// Phase B blends only the first <=8 set bits with recomputed (bit-identical)
// alpha — exact reference semantics including the T>EPS gate.
// ---------------------------------------------------------------------------
__global__ __launch_bounds__(64) void pgr_raster(
    const float* __restrict__ depths, const float4* __restrict__ dat0,
    const float4* __restrict__ dat1, const float* __restrict__ dat2,
    const unsigned* __restrict__ cur, const unsigned* __restrict__ ent,
    float* __restrict__ out)
{
    const int b = blockIdx.z;
    const int t = b * NTILE + blockIdx.y * TDIM + blockIdx.x;
    const int tid = threadIdx.x;
    const int tx0 = blockIdx.x * 8, ty0 = blockIdx.y * 8;
    const int lx = tid & 7, ly = tid >> 3;
    const float px = tx0 + lx + 0.5f, py = ty0 + ly + 0.5f;
    const int bG = b * GN;

    __shared__ unsigned long long s_key[CAP];
    __shared__ float4 s_d0[CAP], s_d1[CAP];
    __shared__ float s_d2[CAP];
    __shared__ unsigned s_ord[CAP];

    // speculative prefetch of entry `tid` (masked index: always in-bounds)
    unsigned eRaw = ent[t * CAP + tid];
    int e = (int)(eRaw & (GN - 1));
    int q = bG + e;
    float myd = depths[q];
    float4 r0 = dat0[q];
    float4 r1 = dat1[q];
    float r2 = dat2[q];
    const int L = min((int)cur[t], CAP);

    unsigned long long myk =
        ((unsigned long long)__float_as_uint(myd) << 13) | (unsigned)e;
    if (tid < L) {
        s_key[tid] = myk;
        s_d0[tid] = r0; s_d1[tid] = r1; s_d2[tid] = r2;   // unsorted slots
    }
    for (int i = 64 + tid; i < L; i += 64) {       // uncommon: L > 64
        int ei = (int)(ent[t * CAP + i] & (GN - 1));
        int qq = bG + ei;
        s_key[i] = ((unsigned long long)__float_as_uint(depths[qq]) << 13)
                   | (unsigned)ei;
        s_d0[i] = dat0[qq]; s_d1[i] = dat1[qq]; s_d2[i] = dat2[qq];
    }
    __syncthreads();

    // sorted-position -> unsorted-slot permutation (exact stable depth order)
    if (tid < L) s_ord[rank_of(s_key, myk, L)] = (unsigned)tid;
    for (int i = 64 + tid; i < L; i += 64)
        s_ord[rank_of(s_key, s_key[i], L)] = (unsigned)i;
    __syncthreads();

    // ---- Phase A: mask pass (no loop-carried deps; 16-wide ILP) ----
    unsigned long long km[4] = {0ull, 0ull, 0ull, 0ull};
    for (int i0 = 0; i0 < L; i0 += 16) {
        #pragma unroll
        for (int k = 0; k < 16; ++k) {
            int idx = i0 + k;
            bool act = idx < L;
            int slot = act ? (int)s_ord[idx] : 0;   // uniform across lanes
            float4 d0 = s_d0[slot];                 // broadcast LDS reads
            float4 d1 = s_d1[slot];
            float dx = __fsub_rn(px, d0.x);
            float dy = __fsub_rn(py, d0.y);
            // sigma = 0.5*((a*dx)*dx + (c*dy)*dy) + (b*dx)*dy (numpy order)
            float t1 = __fmul_rn(__fmul_rn(d0.z, dx), dx);
            float t2 = __fmul_rn(__fmul_rn(d1.x, dy), dy);
            float sigma = __fadd_rn(__fmul_rn(0.5f, __fadd_rn(t1, t2)),
                                    __fmul_rn(__fmul_rn(d0.w, dx), dy));
            bool v = act && sigma >= 0.f && sigma <= 5.55f;  // e^-5.55 < 1/255
            float al = v ? fminf(__fmul_rn(d1.y, expf(-sigma)), 0.999f) : 0.f;
            if (v && al >= ALPHA_T) km[idx >> 6] |= 1ull << (idx & 63);
        }
        int nk = __popcll(km[0]) + __popcll(km[1]) +
                 __popcll(km[2]) + __popcll(km[3]);
        if (__all(nk >= FRONT_K)) break;   // every pixel has its front-8
    }

    // ---- Phase B: blend first <=8 kept (exact reference chain) ----
    float accR = 0.f, accG = 0.f, accB = 0.f, T = 1.f;
    int taken = 0;
    #pragma unroll 1
    for (int w = 0; w < 4; ++w) {
        unsigned long long m = km[w];
        while (m && taken < FRONT_K) {
            int bit = __builtin_ctzll(m);
            m &= m - 1;
            int slot = (int)s_ord[(w << 6) + bit];
            float4 d0 = s_d0[slot];
            float4 d1 = s_d1[slot];
            float dx = __fsub_rn(px, d0.x);
            float dy = __fsub_rn(py, d0.y);
            float t1 = __fmul_rn(__fmul_rn(d0.z, dx), dx);
            float t2 = __fmul_rn(__fmul_rn(d1.x, dy), dy);
            float sigma = __fadd_rn(__fmul_rn(0.5f, __fadd_rn(t1, t2)),
                                    __fmul_rn(__fmul_rn(d0.w, dx), dy));
            float al = fminf(__fmul_rn(d1.y, expf(-sigma)), 0.999f);  // bit-identical
            if (T > EPS_T) {
                float wgt = __fmul_rn(T, al);
                accR += wgt * d1.z;
                accG += wgt * d1.w;
                accB += wgt * s_d2[slot];
            }
            T = __fmul_rn(T, __fsub_rn(1.f, al));
            ++taken;
        }
        if (taken >= FRONT_K) break;
    }

    int o = ((b * HN + (ty0 + ly)) * WN + (tx0 + lx)) * 3;
    out[o] = accR;
    out[o + 1] = accG;
    out[o + 2] = accB;     // bg == 0, so output is accum only
}

extern "C" void kernel_launch(void* const* d_in, const int* in_sizes, int n_in,
                              void* d_out, int out_size, void* d_ws, size_t ws_size,
                              hipStream_t stream) {
    const float* means2d = (const float*)d_in[0];
    const float* conics  = (const float*)d_in[1];
    const float* colors  = (const float*)d_in[2];
    const float* opac    = (const float*)d_in[3];
    const float* depths  = (const float*)d_in[4];
    float* out = (float*)d_out;

    const int BG = BN * GN;
    float4*   dat0 = (float4*)d_ws;                       // 256 KB
    float4*   dat1 = dat0 + BG;                           // 256 KB
    float*    dat2 = (float*)(dat1 + BG);                 //  64 KB
    unsigned* cur  = (unsigned*)(dat2 + BG);              //   8 KB
    unsigned* ent  = cur + BN * NTILE;                    //   2 MB

    pgr_clear<<<(BN * NTILE) / 64, 64, 0, stream>>>(cur);
    pgr_prep<<<BG / 64, 64, 0, stream>>>(means2d, conics, colors, opac,
                                         dat0, dat1, dat2, cur, ent);
    pgr_raster<<<dim3(TDIM, TDIM, BN), 64, 0, stream>>>(
        depths, dat0, dat1, dat2, cur, ent, out);
}

// Round 10
// 46.701 us; speedup vs baseline: 1.2018x; 1.2018x over previous
//
#include <hip/hip_runtime.h>
#include <math.h>

#define GN 8192
#define BN 2
#define HN 256
#define WN 256
#define FRONT_K 8
#define EPS_T 1e-8f
#define ALPHA_T (1.0f / 255.0f)
#define TDIM 32                 // 32x32 tiles of 8x8 px per batch (r7 config — best)
#define NTILE (TDIM * TDIM)
#define CAP 256                 // per-tile list cap (mean ~54)

// ---------------------------------------------------------------------------
// Kernel 0: clear per-tile counters (BN*NTILE = 2048 u32).
// ---------------------------------------------------------------------------
__global__ __launch_bounds__(64) void pgr_clear(unsigned* __restrict__ cur)
{
    cur[blockIdx.x * 64 + threadIdx.x] = 0u;
}

// ---------------------------------------------------------------------------
// Kernel 1: prep + binning. One thread per (batch, gaussian):
//  - repack SoA records (original order)
//  - conservative bbox (alpha>=1/255 <=> sigma<=ln(255*op)) -> tile rect
//    (__logf: rel-err ~1e-7 absorbed by the +1e-4 / +0.02px margins)
//  - atomicAdd-append orig index to covered tiles' lists (append order is
//    irrelevant: raster rank-sorts each list by (depth,idx) deterministically)
// ---------------------------------------------------------------------------
__global__ __launch_bounds__(64) void pgr_prep(
    const float* __restrict__ means2d, const float* __restrict__ conics,
    const float* __restrict__ colors, const float* __restrict__ opac,
    float4* __restrict__ dat0, float4* __restrict__ dat1,
    float* __restrict__ dat2, unsigned* __restrict__ cur,
    unsigned* __restrict__ ent)
{
    int g = blockIdx.x * 64 + threadIdx.x;       // [0, BN*GN)
    int b = g >> 13, i = g & (GN - 1);
    float2 mxy = reinterpret_cast<const float2*>(means2d)[g];
    float mx = mxy.x, my = mxy.y;
    float ca = conics[3 * g], cb = conics[3 * g + 1], cc = conics[3 * g + 2];
    float r = colors[3 * g], g2 = colors[3 * g + 1], b3 = colors[3 * g + 2];
    float op = opac[g];

    dat0[g] = make_float4(mx, my, ca, cb);
    dat1[g] = make_float4(cc, op, r, g2);
    dat2[g] = b3;

    float s = (op > 0.f) ? (__logf(255.0f * op) + 1e-4f) : -1.0f;
    if (s < 0.f) return;                          // alpha < 1/255 everywhere
    float det = fmaxf(ca * cc - cb * cb, 1e-12f);
    float dxm = sqrtf(2.f * s * cc / det) + 0.02f;
    float dym = sqrtf(2.f * s * ca / det) + 0.02f;
    // pixel centers x+0.5 inside [mx-dxm, mx+dxm]; +-1px conservative slack
    int x0 = (int)floorf(mx - dxm - 0.5f), x1 = (int)ceilf(mx + dxm - 0.5f);
    int y0 = (int)floorf(my - dym - 0.5f), y1 = (int)ceilf(my + dym - 0.5f);
    if (x1 < 0 || x0 > WN - 1 || y1 < 0 || y0 > HN - 1) return;
    x0 = max(x0, 0); x1 = min(x1, WN - 1);
    y0 = max(y0, 0); y1 = min(y1, HN - 1);
    int tx0 = x0 >> 3, tx1 = x1 >> 3, ty0 = y0 >> 3, ty1 = y1 >> 3;
    for (int ty = ty0; ty <= ty1; ++ty)
        for (int tx = tx0; tx <= tx1; ++tx) {
            int t = b * NTILE + ty * TDIM + tx;
            unsigned pos = atomicAdd(&cur[t], 1u);
            if (pos < CAP) ent[t * CAP + pos] = (unsigned)i;
        }
}

// rank of key k among s_key[0..L): broadcast LDS reads, no barriers, pipelined
__device__ __forceinline__ int rank_of(const unsigned long long* s_key,
                                       unsigned long long k, int L)
{
    int rank = 0, j = 0;
    for (; j + 4 <= L; j += 4) {
        unsigned long long k0 = s_key[j], k1 = s_key[j + 1];
        unsigned long long k2 = s_key[j + 2], k3 = s_key[j + 3];
        rank += (int)(k0 < k) + (int)(k1 < k) + (int)(k2 < k) + (int)(k3 < k);
    }
    for (; j < L; ++j) rank += (int)(s_key[j] < k);
    return rank;
}

// ---------------------------------------------------------------------------
// Kernel 2: raster. 64 threads = 1 wave = one 8x8 tile (r7 structure = best).
// Lane tid prefetches list entry tid speculatively (masked &8191), computes
// rank = #{smaller (depth,idx) keys} via broadcast LDS reads, scatters its
// record to LDS slot rank == exact stable depth order. Composite in 8-wide
// ILP batches. r10: expf -> __expf (v_exp_f32; ocml expf was ~15 instr +
// branches per eval, ~half the composite issue count).
// ---------------------------------------------------------------------------
__global__ __launch_bounds__(64) void pgr_raster(
    const float* __restrict__ depths, const float4* __restrict__ dat0,
    const float4* __restrict__ dat1, const float* __restrict__ dat2,
    const unsigned* __restrict__ cur, const unsigned* __restrict__ ent,
    float* __restrict__ out)
{
    const int b = blockIdx.z;
    const int t = b * NTILE + blockIdx.y * TDIM + blockIdx.x;
    const int tid = threadIdx.x;
    const int tx0 = blockIdx.x * 8, ty0 = blockIdx.y * 8;
    const int lx = tid & 7, ly = tid >> 3;
    const float px = tx0 + lx + 0.5f, py = ty0 + ly + 0.5f;
    const int bG = b * GN;

    __shared__ unsigned long long s_key[CAP];
    __shared__ float4 s_d0[CAP], s_d1[CAP];
    __shared__ float s_d2[CAP];

    // speculative prefetch of entry `tid` (masked index: always in-bounds)
    unsigned eRaw = ent[t * CAP + tid];
    int e = (int)(eRaw & (GN - 1));
    int q = bG + e;
    float myd = depths[q];
    float4 r0 = dat0[q];
    float4 r1 = dat1[q];
    float r2 = dat2[q];
    const int L = min((int)cur[t], CAP);

    unsigned long long myk =
        ((unsigned long long)__float_as_uint(myd) << 13) | (unsigned)e;
    if (tid < L) s_key[tid] = myk;
    for (int i = 64 + tid; i < L; i += 64) {       // uncommon: L > 64
        int ei = (int)(ent[t * CAP + i] & (GN - 1));
        s_key[i] = ((unsigned long long)__float_as_uint(depths[bG + ei]) << 13)
                   | (unsigned)ei;
    }
    __syncthreads();

    if (tid < L) {
        int rank = rank_of(s_key, myk, L);
        s_d0[rank] = r0; s_d1[rank] = r1; s_d2[rank] = r2;
    }
    for (int i = 64 + tid; i < L; i += 64) {       // uncommon: L > 64
        unsigned long long k = s_key[i];
        int rank = rank_of(s_key, k, L);
        int qq = bG + (int)(k & (GN - 1));
        s_d0[rank] = dat0[qq]; s_d1[rank] = dat1[qq]; s_d2[rank] = dat2[qq];
    }
    __syncthreads();

    float accR = 0.f, accG = 0.f, accB = 0.f, T = 1.f;
    int count = 0;
    bool done = false;

    for (int i0 = 0; i0 < L; i0 += 8) {
        if (__all((int)done)) break;
        float alpha[8], colR[8], colG[8], colB[8];
        bool valid[8];
        // phase 1: 8 independent loads + sigma + exp (ILP hides LDS/exp latency)
        #pragma unroll
        for (int k = 0; k < 8; ++k) {
            int idx = i0 + k;
            bool act = (idx < L) && !done;
            int ii = act ? idx : i0;               // clamped, discarded
            float4 d0 = s_d0[ii];
            float4 d1 = s_d1[ii];
            float dx = __fsub_rn(px, d0.x);
            float dy = __fsub_rn(py, d0.y);
            // sigma = 0.5*((a*dx)*dx + (c*dy)*dy) + (b*dx)*dy (numpy order)
            float t1 = __fmul_rn(__fmul_rn(d0.z, dx), dx);
            float t2 = __fmul_rn(__fmul_rn(d1.x, dy), dy);
            float sigma = __fadd_rn(__fmul_rn(0.5f, __fadd_rn(t1, t2)),
                                    __fmul_rn(__fmul_rn(d0.w, dx), dy));
            bool v = act && sigma >= 0.f && sigma <= 5.55f;  // e^-5.55 < 1/255
            float al = v ? fminf(__fmul_rn(d1.y, __expf(-sigma)), 0.999f) : 0.f;
            valid[k] = v && (al >= ALPHA_T);
            alpha[k] = al;
            colR[k] = d1.z; colG[k] = d1.w; colB[k] = s_d2[ii];
        }
        // phase 2: serial front-to-back blend (exact reference semantics)
        #pragma unroll
        for (int k = 0; k < 8; ++k) {
            if (valid[k] && !done) {
                float al = alpha[k];
                if (T > EPS_T) {
                    float w = __fmul_rn(T, al);
                    accR += w * colR[k];
                    accG += w * colG[k];
                    accB += w * colB[k];
                }
                T = __fmul_rn(T, __fsub_rn(1.f, al));
                count++;
                if (count >= FRONT_K || T <= EPS_T) done = true;
            }
        }
    }

    int o = ((b * HN + (ty0 + ly)) * WN + (tx0 + lx)) * 3;
    out[o] = accR;
    out[o + 1] = accG;
    out[o + 2] = accB;     // bg == 0, so output is accum only
}

extern "C" void kernel_launch(void* const* d_in, const int* in_sizes, int n_in,
                              void* d_out, int out_size, void* d_ws, size_t ws_size,
                              hipStream_t stream) {
    const float* means2d = (const float*)d_in[0];
    const float* conics  = (const float*)d_in[1];
    const float* colors  = (const float*)d_in[2];
    const float* opac    = (const float*)d_in[3];
    const float* depths  = (const float*)d_in[4];
    float* out = (float*)d_out;

    const int BG = BN * GN;
    float4*   dat0 = (float4*)d_ws;                       // 256 KB
    float4*   dat1 = dat0 + BG;                           // 256 KB
    float*    dat2 = (float*)(dat1 + BG);                 //  64 KB
    unsigned* cur  = (unsigned*)(dat2 + BG);              //   8 KB
    unsigned* ent  = cur + BN * NTILE;                    //   2 MB

    pgr_clear<<<(BN * NTILE) / 64, 64, 0, stream>>>(cur);
    pgr_prep<<<BG / 64, 64, 0, stream>>>(means2d, conics, colors, opac,
                                         dat0, dat1, dat2, cur, ent);
    pgr_raster<<<dim3(TDIM, TDIM, BN), 64, 0, stream>>>(
        depths, dat0, dat1, dat2, cur, ent, out);
}